// Round 1
// baseline (304.369 us; speedup 1.0000x reference)
//
#include <hip/hip_runtime.h>
#include <hip/hip_bf16.h>
#include <math.h>

#define EPSF 1e-6f
#define MAX_ACOSH_ARGF 1e6f
#define MAX_DISTF 50.0f
#define TINYF 1e-15f

constexpr int B_ = 2, T_ = 512, D_ = 512, H_ = 8, N_ = 32, A_ = 33;
constexpr int QSZ = B_ * H_ * T_ * A_;   // 270336 floats per tensor

// ---------------- Kernel 1: QKV GEMM + hyperboloid lift ----------------
__global__ __launch_bounds__(256) void lift_kernel(
    const float* __restrict__ x,
    const float* __restrict__ Wq, const float* __restrict__ bq,
    const float* __restrict__ Wk, const float* __restrict__ bk,
    const float* __restrict__ Wv, const float* __restrict__ bv,
    float* __restrict__ Q, float* __restrict__ K, float* __restrict__ V)
{
    __shared__ float xs[512];
    __shared__ float us[768];
    const int bt  = blockIdx.x;            // b*T + t
    const int b   = bt >> 9;
    const int t   = bt & 511;
    const int tid = threadIdx.x;

    for (int i = tid; i < 512; i += 256) xs[i] = x[bt * 512 + i];
    __syncthreads();

    for (int j = tid; j < 768; j += 256) {
        const int tensor = j >> 8;         // 0=q 1=k 2=v
        const int col    = j & 255;
        const float* W    = (tensor == 0) ? Wq : (tensor == 1) ? Wk : Wv;
        const float* bias = (tensor == 0) ? bq : (tensor == 1) ? bk : bv;
        float acc = bias[col];
        #pragma unroll 8
        for (int d = 0; d < 512; ++d)
            acc = fmaf(xs[d], W[d * 256 + col], acc);
        us[j] = acc;
    }
    __syncthreads();

    // lift: 24 groups (tensor,h) of 32 spatial comps each
    const int lane32 = tid & 31;
    for (int p = 0; p < 3; ++p) {
        const int g = p * 8 + (tid >> 5);  // 0..23
        const float u = us[g * 32 + lane32];
        float n2 = u * u;
        #pragma unroll
        for (int m = 1; m < 32; m <<= 1) n2 += __shfl_xor(n2, m, 32);
        const float vn = sqrtf(fmaxf(n2, TINYF));
        const float ch = coshf(vn);
        const float sh = sinhf(vn) / fmaxf(vn, TINYF);
        const float yi = sh * u;
        const float xx = fmaf(sh * sh, n2, -ch * ch);  // mink(y,y) ~ -1
        const float scale = sqrtf(fmaxf(fabsf(xx), TINYF));
        const int tensor = g >> 3, h = g & 7;
        float* out = (tensor == 0) ? Q : (tensor == 1) ? K : V;
        const int base = ((b * H_ + h) * T_ + t) * A_;
        out[base + 1 + lane32] = yi / scale;
        if (lane32 == 0) out[base] = fabsf(ch / scale);
    }
}

// ---------------- Kernel 2: attention + Karcher step + log-map ----------------
__global__ __launch_bounds__(64) void attn_kernel(
    const float* __restrict__ Q, const float* __restrict__ K,
    const float* __restrict__ V, float* __restrict__ ZT)
{
    const int blk  = blockIdx.x;           // (b*H+h)*T + q
    const int bh   = blk >> 9;
    const int qi   = blk & 511;
    const int b    = bh >> 3;
    const int h    = bh & 7;
    const int lane = threadIdx.x;          // 0..63, one wave

    __shared__ float qs[A_];
    if (lane < A_) qs[lane] = Q[(bh * T_ + qi) * A_ + lane];
    __syncthreads();

    float m = -3.0e38f, l = 0.0f;
    float acc[A_];
    #pragma unroll
    for (int a = 0; a < A_; ++a) acc[a] = 0.0f;

    const float* Kb = K + bh * T_ * A_;
    const float* Vb = V + bh * T_ * A_;

    for (int k0 = 0; k0 < T_; k0 += 64) {
        const int k = k0 + lane;
        const float* kr = Kb + k * A_;
        const float* vr = Vb + k * A_;
        float vreg[A_];
        vreg[0] = vr[0];
        float a1 = qs[0] * kr[0];
        float a2 = qs[0] * vreg[0];
        #pragma unroll
        for (int i = 1; i < A_; ++i) {
            const float ki = kr[i];
            vreg[i] = vr[i];
            a1 = fmaf(-qs[i], ki, a1);
            a2 = fmaf(-qs[i], vreg[i], a2);
        }
        const float a1c = fminf(fmaxf(a1, 1.0f + EPSF), MAX_ACOSH_ARGF);
        const float d1  = fminf(acoshf(a1c), MAX_DISTF);
        const float s   = -d1 * d1;
        const float a2c = fminf(fmaxf(a2, 1.0f + EPSF), MAX_ACOSH_ARGF);
        const float d2  = acoshf(a2c);

        const float mn   = fmaxf(m, s);
        const float corr = expf(m - mn);
        const float e    = expf(s - mn);
        l = l * corr + e;
        const float w = e * d2;
        #pragma unroll
        for (int a = 0; a < A_; ++a)
            acc[a] = fmaf(acc[a], corr, w * fmaf(a2c, qs[a], vreg[a]));
        m = mn;
    }

    // 64-lane butterfly merge of (m, l, acc[33]) -> all lanes identical
    #pragma unroll
    for (int msk = 1; msk < 64; msk <<= 1) {
        const float m2 = __shfl_xor(m, msk, 64);
        const float l2 = __shfl_xor(l, msk, 64);
        const float mn = fmaxf(m, m2);
        const float c1 = expf(m - mn);
        const float c2 = expf(m2 - mn);
        l = l * c1 + l2 * c2;
        #pragma unroll
        for (int a = 0; a < A_; ++a) {
            const float o = __shfl_xor(acc[a], msk, 64);
            acc[a] = acc[a] * c1 + o * c2;
        }
        m = mn;
    }

    // epilogue (every lane redundantly; lanes 0..32 write)
    const float un_const = sqrtf(TINYF);          // = sqrt(max(mink(u,u),TINY)) always (mink<=-4)
    const float inv_l = 1.0f / l;

    // step = (1/sqrt(TINY)) * sum_k attn*d2*(V + a2c*Q)
    #pragma unroll
    for (int a = 0; a < A_; ++a) acc[a] = (acc[a] * inv_l) / un_const;

    float mk = -acc[0] * acc[0];
    #pragma unroll
    for (int a = 1; a < A_; ++a) mk = fmaf(acc[a], acc[a], mk);
    const float snorm = sqrtf(fmaxf(mk, TINYF));
    const float fac   = fminf(snorm, 20.0f) / (snorm + 1e-9f);
    #pragma unroll
    for (int a = 0; a < A_; ++a) acc[a] *= fac;

    // exp_map(Q, step)
    float mk2 = -acc[0] * acc[0];
    #pragma unroll
    for (int a = 1; a < A_; ++a) mk2 = fmaf(acc[a], acc[a], mk2);
    const float vn  = sqrtf(fmaxf(mk2, TINYF));
    const float ch  = coshf(vn);
    const float shr = sinhf(vn) / fmaxf(vn, TINYF);
    #pragma unroll
    for (int a = 0; a < A_; ++a) acc[a] = fmaf(ch, qs[a], shr * acc[a]);  // y

    float xx = -acc[0] * acc[0];
    #pragma unroll
    for (int a = 1; a < A_; ++a) xx = fmaf(acc[a], acc[a], xx);
    const float scale = sqrtf(fmaxf(fabsf(xx), TINYF));

    const float Y0  = fabsf(acc[0] / scale);
    const float al3 = fminf(fmaxf(Y0, 1.0f + EPSF), MAX_ACOSH_ARGF);
    const float d3  = acoshf(al3);
    const float u0  = Y0 + al3;

    // mink(u,u) = -u0^2 + sum Y_i^2  (robustly negative -> un = sqrt(TINY))
    const float f3 = d3 / fmaxf(un_const, TINYF);

    if (lane < A_) {
        const float Ya = acc[lane] / scale;
        const float zt = (lane == 0) ? f3 * u0 : f3 * Ya;
        ZT[(b * T_ + qi) * (H_ * A_) + h * A_ + lane] = zt;
    }
}

// ---------------- Kernel 3: Z = Z_tan @ Wo + bo ----------------
__global__ __launch_bounds__(256) void out_kernel(
    const float* __restrict__ ZT, const float* __restrict__ Wo,
    const float* __restrict__ bo, float* __restrict__ out)
{
    __shared__ float zs[H_ * A_];
    const int bt  = blockIdx.x;
    const int tid = threadIdx.x;
    for (int i = tid; i < H_ * A_; i += 256) zs[i] = ZT[bt * (H_ * A_) + i];
    __syncthreads();
    for (int d = tid; d < 512; d += 256) {
        float accv = bo[d];
        #pragma unroll 8
        for (int k = 0; k < H_ * A_; ++k)
            accv = fmaf(zs[k], Wo[k * 512 + d], accv);
        out[bt * 512 + d] = accv;
    }
}

extern "C" void kernel_launch(void* const* d_in, const int* in_sizes, int n_in,
                              void* d_out, int out_size, void* d_ws, size_t ws_size,
                              hipStream_t stream) {
    const float* x  = (const float*)d_in[0];
    const float* Wq = (const float*)d_in[1];
    const float* bq = (const float*)d_in[2];
    const float* Wk = (const float*)d_in[3];
    const float* bk = (const float*)d_in[4];
    const float* Wv = (const float*)d_in[5];
    const float* bv = (const float*)d_in[6];
    const float* Wo = (const float*)d_in[7];
    const float* bo = (const float*)d_in[8];
    float* out = (float*)d_out;
    float* ws  = (float*)d_ws;

    float* Q  = ws;
    float* K  = ws + QSZ;
    float* V  = ws + 2 * QSZ;
    float* ZT = ws + 3 * QSZ;

    lift_kernel<<<B_ * T_, 256, 0, stream>>>(x, Wq, bq, Wk, bk, Wv, bv, Q, K, V);
    attn_kernel<<<B_ * H_ * T_, 64, 0, stream>>>(Q, K, V, ZT);
    out_kernel<<<B_ * T_, 256, 0, stream>>>(ZT, Wo, bo, out);
}

// Round 2
// 264.402 us; speedup vs baseline: 1.1512x; 1.1512x over previous
//
#include <hip/hip_runtime.h>
#include <hip/hip_bf16.h>
#include <math.h>

#define EPSF 1e-6f
#define MAX_ACOSH_ARGF 1e6f
#define MAX_DISTF 50.0f
#define TINYF 1e-15f

constexpr int B_ = 2, T_ = 512, D_ = 512, H_ = 8, N_ = 32, A_ = 33;
constexpr int QSZ = B_ * H_ * T_ * A_;   // 270336 floats per tensor
constexpr int HA = H_ * A_;              // 264

__device__ __forceinline__ float facosh(float a) {
    // a >= 1+EPS guaranteed by clamp; (a-1)(a+1) avoids a*a-1 cancellation
    return __logf(a + sqrtf((a - 1.0f) * (a + 1.0f)));
}

// ---------------- Kernel 1: QKV GEMM (64x64 tile) + fused hyperboloid lift ----
__global__ __launch_bounds__(256) void qkv_lift_kernel(
    const float* __restrict__ x,
    const float* __restrict__ Wq, const float* __restrict__ bq,
    const float* __restrict__ Wk, const float* __restrict__ bk,
    const float* __restrict__ Wv, const float* __restrict__ bv,
    float* __restrict__ Q, float* __restrict__ K, float* __restrict__ V)
{
    __shared__ float smem[4384];          // union: xs[64][36]+wt[32][65] | Ct[64][65]
    float* xs = smem;                     // [64][36]
    float* wt = smem + 2304;              // [32][65]
    float* Ct = smem;                     // [64][65] (reused after loop)

    const int m0  = blockIdx.x * 64;      // bt tile
    const int ny  = blockIdx.y;           // 0..11
    const int tsel = ny >> 2;             // 0=q 1=k 2=v
    const int n0t  = (ny & 3) * 64;       // col offset within tensor (0..192)
    const float* W    = (tsel == 0) ? Wq : (tsel == 1) ? Wk : Wv;
    const float* bias = (tsel == 0) ? bq : (tsel == 1) ? bk : bv;
    float* OUT        = (tsel == 0) ? Q  : (tsel == 1) ? K  : V;

    const int tid = threadIdx.x;
    const int tx = tid & 15, ty = tid >> 4;

    float acc[4][4];
    #pragma unroll
    for (int j = 0; j < 4; ++j) {
        const float bv_ = bias[n0t + tx + 16 * j];
        #pragma unroll
        for (int i = 0; i < 4; ++i) acc[i][j] = bv_;
    }

    for (int kb = 0; kb < 512; kb += 32) {
        __syncthreads();
        // stage x tile: 64 rows x 32 k  (512 float4)
        for (int idx = tid; idx < 512; idx += 256) {
            const int r = idx >> 3, c4 = idx & 7;
            const float4 v = *(const float4*)(x + (m0 + r) * 512 + kb + c4 * 4);
            *(float4*)(xs + r * 36 + c4 * 4) = v;
        }
        // stage W tile: 32 k x 64 cols (512 float4 -> scalar LDS writes, pad 65)
        for (int idx = tid; idx < 512; idx += 256) {
            const int kk = idx >> 4, c4 = idx & 15;
            const float4 v = *(const float4*)(W + (kb + kk) * 256 + n0t + c4 * 4);
            float* dst = wt + kk * 65 + c4 * 4;
            dst[0] = v.x; dst[1] = v.y; dst[2] = v.z; dst[3] = v.w;
        }
        __syncthreads();
        #pragma unroll 8
        for (int kk = 0; kk < 32; ++kk) {
            float a[4], bb[4];
            #pragma unroll
            for (int i = 0; i < 4; ++i) a[i] = xs[(ty + 16 * i) * 36 + kk];
            #pragma unroll
            for (int j = 0; j < 4; ++j) bb[j] = wt[kk * 65 + tx + 16 * j];
            #pragma unroll
            for (int i = 0; i < 4; ++i)
                #pragma unroll
                for (int j = 0; j < 4; ++j)
                    acc[i][j] = fmaf(a[i], bb[j], acc[i][j]);
        }
    }
    __syncthreads();
    #pragma unroll
    for (int i = 0; i < 4; ++i)
        #pragma unroll
        for (int j = 0; j < 4; ++j)
            Ct[(ty + 16 * i) * 65 + tx + 16 * j] = acc[i][j];
    __syncthreads();

    if (tid < 128) {
        const int row = tid >> 1, g = tid & 1;  // 64 rows x 2 head-groups
        const float* u = Ct + row * 65 + g * 32;
        float n2 = 0.0f;
        #pragma unroll
        for (int kk = 0; kk < 32; ++kk) n2 = fmaf(u[kk], u[kk], n2);
        n2 = fmaxf(n2, TINYF);
        const float vn = sqrtf(n2);
        const float ch = coshf(vn);
        const float sh = sinhf(vn) / fmaxf(vn, TINYF);
        const float xx = fmaf(sh * sh, n2, -ch * ch);       // mink(y,y) ~ -1
        const float scale = sqrtf(fmaxf(fabsf(xx), TINYF));
        const int bt = m0 + row;
        const int b = bt >> 9, t = bt & 511;
        const int h = (n0t >> 5) + g;
        const int base = ((b * H_ + h) * T_ + t) * A_;
        OUT[base] = fabsf(ch / scale);
        const float fs = sh / scale;
        #pragma unroll
        for (int kk = 0; kk < 32; ++kk) OUT[base + 1 + kk] = fs * u[kk];
    }
}

// ---------------- Kernel 2: attention + Karcher step + log-map ----------------
// 512 threads = 8 waves; one bh per block, 8 consecutive q's (one per wave);
// K/V staged in LDS chunks of 64 rows shared by all 8 waves.
__global__ __launch_bounds__(512, 4) void attn_kernel(
    const float* __restrict__ Q, const float* __restrict__ K,
    const float* __restrict__ V, float* __restrict__ ZT)
{
    __shared__ float4 kv4[1056 + 66];     // K chunk 528 f4 | V chunk 528 f4 | q 66 f4
    float* kch = (float*)kv4;             // [64][33]
    float* vch = kch + 2112;              // [64][33]
    float* qld = kch + 4224;              // [8][33]

    const int blk  = blockIdx.x;          // 1024 blocks
    const int bh   = blk >> 6;            // 0..15
    const int q0   = (blk & 63) * 8;
    const int tid  = threadIdx.x;
    const int wid  = tid >> 6;
    const int lane = tid & 63;

    const float* Kb = K + bh * (T_ * A_);
    const float* Vb = V + bh * (T_ * A_);

    if (tid < 66) kv4[1056 + tid] = *((const float4*)(Q + (bh * T_ + q0) * A_) + tid);
    __syncthreads();

    float qr[A_];
    #pragma unroll
    for (int a = 0; a < A_; ++a) qr[a] = qld[wid * A_ + a];  // wave-uniform broadcast

    float m = -3.0e38f, l = 0.0f, sacc = 0.0f;
    float acc[A_];
    #pragma unroll
    for (int a = 0; a < A_; ++a) acc[a] = 0.0f;

    for (int c = 0; c < 8; ++c) {
        __syncthreads();
        {
            const float4* Ks = (const float4*)(Kb + c * 64 * A_);
            const float4* Vs = (const float4*)(Vb + c * 64 * A_);
            for (int idx = tid; idx < 1056; idx += 512)
                kv4[idx] = (idx < 528) ? Ks[idx] : Vs[idx - 528];
        }
        __syncthreads();

        const float* kr = kch + lane * A_;   // stride 33 (odd) -> 2-way banks (free)
        const float* vr = vch + lane * A_;
        float a1 = qr[0] * kr[0];
        float a2 = qr[0] * vr[0];
        #pragma unroll
        for (int i = 1; i < A_; ++i) {
            a1 = fmaf(-qr[i], kr[i], a1);
            a2 = fmaf(-qr[i], vr[i], a2);
        }
        const float a1c = fminf(fmaxf(a1, 1.0f + EPSF), MAX_ACOSH_ARGF);
        const float d1  = fminf(facosh(a1c), MAX_DISTF);
        const float s   = -d1 * d1;
        const float a2c = fminf(fmaxf(a2, 1.0f + EPSF), MAX_ACOSH_ARGF);
        const float d2  = facosh(a2c);

        const float mn   = fmaxf(m, s);
        const float corr = __expf(m - mn);
        const float e    = __expf(s - mn);
        l = fmaf(l, corr, e);
        const float w = e * d2;
        sacc = fmaf(sacc, corr, w * a2c);
        #pragma unroll
        for (int a = 0; a < A_; ++a)
            acc[a] = fmaf(acc[a], corr, w * vr[a]);   // V re-read from LDS (no vreg)
        m = mn;
    }

    // fold the scalar Q-side accumulator:  step ∝ Σw·V + (Σw·a2c)·Q
    #pragma unroll
    for (int a = 0; a < A_; ++a) acc[a] = fmaf(sacc, qr[a], acc[a]);

    // 64-lane butterfly merge of (m, l, acc[33])
    #pragma unroll
    for (int msk = 1; msk < 64; msk <<= 1) {
        const float m2 = __shfl_xor(m, msk, 64);
        const float l2 = __shfl_xor(l, msk, 64);
        const float mn = fmaxf(m, m2);
        const float c1 = __expf(m - mn);
        const float c2 = __expf(m2 - mn);
        l = l * c1 + l2 * c2;
        #pragma unroll
        for (int a = 0; a < A_; ++a) {
            const float o = __shfl_xor(acc[a], msk, 64);
            acc[a] = acc[a] * c1 + o * c2;
        }
        m = mn;
    }

    // epilogue (library coshf/sinhf/acoshf: small-arg-safe, once per wave)
    const float un_const = sqrtf(TINYF);
    const float inv_l = 1.0f / l;
    #pragma unroll
    for (int a = 0; a < A_; ++a) acc[a] = (acc[a] * inv_l) / un_const;

    float mk = -acc[0] * acc[0];
    #pragma unroll
    for (int a = 1; a < A_; ++a) mk = fmaf(acc[a], acc[a], mk);
    const float snorm = sqrtf(fmaxf(mk, TINYF));
    const float fac   = fminf(snorm, 20.0f) / (snorm + 1e-9f);
    #pragma unroll
    for (int a = 0; a < A_; ++a) acc[a] *= fac;

    float mk2 = -acc[0] * acc[0];
    #pragma unroll
    for (int a = 1; a < A_; ++a) mk2 = fmaf(acc[a], acc[a], mk2);
    const float vn  = sqrtf(fmaxf(mk2, TINYF));
    const float ch  = coshf(vn);
    const float shr = sinhf(vn) / fmaxf(vn, TINYF);
    #pragma unroll
    for (int a = 0; a < A_; ++a) acc[a] = fmaf(ch, qr[a], shr * acc[a]);  // y

    float xx = -acc[0] * acc[0];
    #pragma unroll
    for (int a = 1; a < A_; ++a) xx = fmaf(acc[a], acc[a], xx);
    const float scale = sqrtf(fmaxf(fabsf(xx), TINYF));

    const float Y0  = fabsf(acc[0] / scale);
    const float al3 = fminf(fmaxf(Y0, 1.0f + EPSF), MAX_ACOSH_ARGF);
    const float d3  = acoshf(al3);
    const float u0  = Y0 + al3;
    const float f3  = d3 / fmaxf(un_const, TINYF);

    if (lane < A_) {
        const float Ya = acc[lane] / scale;
        const float zt = (lane == 0) ? f3 * u0 : f3 * Ya;
        const int b = bh >> 3, h = bh & 7, qi = q0 + wid;
        ZT[(b * T_ + qi) * HA + h * A_ + lane] = zt;
    }
}

// ---------------- Kernel 3: Z = Z_tan @ Wo + bo (64x64 tile, BK=44) -----------
__global__ __launch_bounds__(256) void out_kernel(
    const float* __restrict__ ZT, const float* __restrict__ Wo,
    const float* __restrict__ bo, float* __restrict__ out)
{
    __shared__ float smem[2816 + 2860];
    float* zs = smem;            // [64][44]
    float* wt = smem + 2816;     // [44][65]
    const int m0 = blockIdx.x * 64, n0 = blockIdx.y * 64;
    const int tid = threadIdx.x;
    const int tx = tid & 15, ty = tid >> 4;

    float acc[4][4];
    #pragma unroll
    for (int j = 0; j < 4; ++j) {
        const float bv_ = bo[n0 + tx + 16 * j];
        #pragma unroll
        for (int i = 0; i < 4; ++i) acc[i][j] = bv_;
    }

    for (int kb = 0; kb < HA; kb += 44) {
        __syncthreads();
        for (int idx = tid; idx < 704; idx += 256) {        // zs: 64 x 11 float4
            const int r = idx / 11, c4 = idx % 11;
            const float4 v = *(const float4*)(ZT + (m0 + r) * HA + kb + c4 * 4);
            *(float4*)(zs + r * 44 + c4 * 4) = v;
        }
        for (int idx = tid; idx < 704; idx += 256) {        // wt: 44 x 16 float4
            const int kk = idx >> 4, c4 = idx & 15;
            const float4 v = *(const float4*)(Wo + (kb + kk) * 512 + n0 + c4 * 4);
            float* dst = wt + kk * 65 + c4 * 4;
            dst[0] = v.x; dst[1] = v.y; dst[2] = v.z; dst[3] = v.w;
        }
        __syncthreads();
        #pragma unroll 4
        for (int kk = 0; kk < 44; ++kk) {
            float a[4], bb[4];
            #pragma unroll
            for (int i = 0; i < 4; ++i) a[i] = zs[(ty + 16 * i) * 44 + kk];
            #pragma unroll
            for (int j = 0; j < 4; ++j) bb[j] = wt[kk * 65 + tx + 16 * j];
            #pragma unroll
            for (int i = 0; i < 4; ++i)
                #pragma unroll
                for (int j = 0; j < 4; ++j)
                    acc[i][j] = fmaf(a[i], bb[j], acc[i][j]);
        }
    }
    #pragma unroll
    for (int i = 0; i < 4; ++i)
        #pragma unroll
        for (int j = 0; j < 4; ++j)
            out[(m0 + ty + 16 * i) * 512 + n0 + tx + 16 * j] = acc[i][j];
}

extern "C" void kernel_launch(void* const* d_in, const int* in_sizes, int n_in,
                              void* d_out, int out_size, void* d_ws, size_t ws_size,
                              hipStream_t stream) {
    const float* x  = (const float*)d_in[0];
    const float* Wq = (const float*)d_in[1];
    const float* bq = (const float*)d_in[2];
    const float* Wk = (const float*)d_in[3];
    const float* bk = (const float*)d_in[4];
    const float* Wv = (const float*)d_in[5];
    const float* bv = (const float*)d_in[6];
    const float* Wo = (const float*)d_in[7];
    const float* bo = (const float*)d_in[8];
    float* out = (float*)d_out;
    float* ws  = (float*)d_ws;

    float* Q  = ws;
    float* K  = ws + QSZ;
    float* V  = ws + 2 * QSZ;
    float* ZT = ws + 3 * QSZ;

    qkv_lift_kernel<<<dim3(16, 12), 256, 0, stream>>>(x, Wq, bq, Wk, bk, Wv, bv, Q, K, V);
    attn_kernel<<<1024, 512, 0, stream>>>(Q, K, V, ZT);
    out_kernel<<<dim3(16, 8), 256, 0, stream>>>(ZT, Wo, bo, out);
}

// Round 3
// 216.629 us; speedup vs baseline: 1.4050x; 1.2205x over previous
//
#include <hip/hip_runtime.h>
#include <hip/hip_bf16.h>
#include <math.h>

#define EPSF 1e-6f
#define MAX_ACOSH_ARGF 1e6f
#define MAX_DISTF 50.0f
#define TINYF 1e-15f

constexpr int B_ = 2, T_ = 512, D_ = 512, H_ = 8, N_ = 32, A_ = 33;
constexpr int QSZ = B_ * H_ * T_ * A_;   // 270336 floats per tensor
constexpr int HA = H_ * A_;              // 264

__device__ __forceinline__ float facosh(float a) {
    // a >= 1+EPS guaranteed by clamp; (a-1)(a+1) avoids a*a-1 cancellation
    return __logf(a + sqrtf((a - 1.0f) * (a + 1.0f)));
}

__device__ __forceinline__ float bcast_first(float x) {
    return __int_as_float(__builtin_amdgcn_readfirstlane(__float_as_int(x)));
}

// ---------------- Kernel 1: QKV GEMM (64x64 tile) + fused hyperboloid lift ----
__global__ __launch_bounds__(256) void qkv_lift_kernel(
    const float* __restrict__ x,
    const float* __restrict__ Wq, const float* __restrict__ bq,
    const float* __restrict__ Wk, const float* __restrict__ bk,
    const float* __restrict__ Wv, const float* __restrict__ bv,
    float* __restrict__ Q, float* __restrict__ K, float* __restrict__ V)
{
    __shared__ float smem[4384];          // union: xs[64][36]+wt[32][65] | Ct[64][65]
    float* xs = smem;                     // [64][36]
    float* wt = smem + 2304;              // [32][65]
    float* Ct = smem;                     // [64][65] (reused after loop)

    const int m0  = blockIdx.x * 64;      // bt tile
    const int ny  = blockIdx.y;           // 0..11
    const int tsel = ny >> 2;             // 0=q 1=k 2=v
    const int n0t  = (ny & 3) * 64;       // col offset within tensor (0..192)
    const float* W    = (tsel == 0) ? Wq : (tsel == 1) ? Wk : Wv;
    const float* bias = (tsel == 0) ? bq : (tsel == 1) ? bk : bv;
    float* OUT        = (tsel == 0) ? Q  : (tsel == 1) ? K  : V;

    const int tid = threadIdx.x;
    const int tx = tid & 15, ty = tid >> 4;

    float acc[4][4];
    #pragma unroll
    for (int j = 0; j < 4; ++j) {
        const float bv_ = bias[n0t + tx + 16 * j];
        #pragma unroll
        for (int i = 0; i < 4; ++i) acc[i][j] = bv_;
    }

    for (int kb = 0; kb < 512; kb += 32) {
        __syncthreads();
        for (int idx = tid; idx < 512; idx += 256) {
            const int r = idx >> 3, c4 = idx & 7;
            const float4 v = *(const float4*)(x + (m0 + r) * 512 + kb + c4 * 4);
            *(float4*)(xs + r * 36 + c4 * 4) = v;
        }
        for (int idx = tid; idx < 512; idx += 256) {
            const int kk = idx >> 4, c4 = idx & 15;
            const float4 v = *(const float4*)(W + (kb + kk) * 256 + n0t + c4 * 4);
            float* dst = wt + kk * 65 + c4 * 4;
            dst[0] = v.x; dst[1] = v.y; dst[2] = v.z; dst[3] = v.w;
        }
        __syncthreads();
        #pragma unroll 8
        for (int kk = 0; kk < 32; ++kk) {
            float a[4], bb[4];
            #pragma unroll
            for (int i = 0; i < 4; ++i) a[i] = xs[(ty + 16 * i) * 36 + kk];
            #pragma unroll
            for (int j = 0; j < 4; ++j) bb[j] = wt[kk * 65 + tx + 16 * j];
            #pragma unroll
            for (int i = 0; i < 4; ++i)
                #pragma unroll
                for (int j = 0; j < 4; ++j)
                    acc[i][j] = fmaf(a[i], bb[j], acc[i][j]);
        }
    }
    __syncthreads();
    #pragma unroll
    for (int i = 0; i < 4; ++i)
        #pragma unroll
        for (int j = 0; j < 4; ++j)
            Ct[(ty + 16 * i) * 65 + tx + 16 * j] = acc[i][j];
    __syncthreads();

    if (tid < 128) {
        const int row = tid >> 1, g = tid & 1;  // 64 rows x 2 head-groups
        const float* u = Ct + row * 65 + g * 32;
        float n2 = 0.0f;
        #pragma unroll
        for (int kk = 0; kk < 32; ++kk) n2 = fmaf(u[kk], u[kk], n2);
        n2 = fmaxf(n2, TINYF);
        const float vn = sqrtf(n2);
        const float ch = coshf(vn);
        const float sh = sinhf(vn) / fmaxf(vn, TINYF);
        const float xx = fmaf(sh * sh, n2, -ch * ch);       // mink(y,y) ~ -1
        const float scale = sqrtf(fmaxf(fabsf(xx), TINYF));
        const int bt = m0 + row;
        const int b = bt >> 9, t = bt & 511;
        const int h = (n0t >> 5) + g;
        const int base = ((b * H_ + h) * T_ + t) * A_;
        OUT[base] = fabsf(ch / scale);
        const float fs = sh / scale;
        #pragma unroll
        for (int kk = 0; kk < 32; ++kk) OUT[base + 1 + kk] = fs * u[kk];
    }
}

// ---------------- Kernel 2: attention + Karcher step + log-map ----------------
// 512 threads = 8 waves; one bh per block, 8 consecutive q's (one per wave);
// K/V staged in LDS chunks of 64 rows shared by all 8 waves.
// q-row lives in SGPRs (readfirstlane); acc[] only ever statically indexed.
__global__ __launch_bounds__(512, 4) void attn_kernel(
    const float* __restrict__ Q, const float* __restrict__ K,
    const float* __restrict__ V, float* __restrict__ ZT)
{
    __shared__ float4 kv4[1056 + 66];     // K chunk 528 f4 | V chunk 528 f4 | q 66 f4
    float* kch = (float*)kv4;             // [64][33]
    float* vch = kch + 2112;              // [64][33]
    float* qld = kch + 4224;              // [8][33]

    const int blk  = blockIdx.x;          // 1024 blocks
    const int bh   = blk >> 6;            // 0..15
    const int q0   = (blk & 63) * 8;
    const int tid  = threadIdx.x;
    const int wid  = tid >> 6;
    const int lane = tid & 63;

    const float* Kb = K + bh * (T_ * A_);
    const float* Vb = V + bh * (T_ * A_);

    if (tid < 66) kv4[1056 + tid] = *((const float4*)(Q + (bh * T_ + q0) * A_) + tid);
    __syncthreads();

    // wave-uniform q row -> SGPRs
    float qr[A_];
    #pragma unroll
    for (int a = 0; a < A_; ++a) qr[a] = bcast_first(qld[wid * A_ + a]);

    float m = -3.0e38f, l = 0.0f, sacc = 0.0f;
    float acc[A_];
    #pragma unroll
    for (int a = 0; a < A_; ++a) acc[a] = 0.0f;

    for (int c = 0; c < 8; ++c) {
        __syncthreads();
        {
            const float4* Ks = (const float4*)(Kb + c * 64 * A_);
            const float4* Vs = (const float4*)(Vb + c * 64 * A_);
            for (int idx = tid; idx < 1056; idx += 512)
                kv4[idx] = (idx < 528) ? Ks[idx] : Vs[idx - 528];
        }
        __syncthreads();

        const float* kr = kch + lane * A_;   // stride 33 (odd) -> conflict-free
        const float* vr = vch + lane * A_;
        float vg[A_];                         // transient: live within this iter only
        vg[0] = vr[0];
        float a1 = qr[0] * kr[0];
        float a2 = qr[0] * vg[0];
        #pragma unroll
        for (int i = 1; i < A_; ++i) {
            vg[i] = vr[i];
            a1 = fmaf(-qr[i], kr[i], a1);
            a2 = fmaf(-qr[i], vg[i], a2);
        }
        const float a1c = fminf(fmaxf(a1, 1.0f + EPSF), MAX_ACOSH_ARGF);
        const float d1  = fminf(facosh(a1c), MAX_DISTF);
        const float s   = -d1 * d1;
        const float a2c = fminf(fmaxf(a2, 1.0f + EPSF), MAX_ACOSH_ARGF);
        const float d2  = facosh(a2c);

        const float mn   = fmaxf(m, s);
        const float corr = __expf(m - mn);
        const float e    = __expf(s - mn);
        l = fmaf(l, corr, e);
        const float w = e * d2;
        sacc = fmaf(sacc, corr, w * a2c);
        #pragma unroll
        for (int a = 0; a < A_; ++a)
            acc[a] = fmaf(acc[a], corr, w * vg[a]);
        m = mn;
    }

    // ---- wave merge: global max, scale once, plain butterfly sums ----
    float M = m;
    #pragma unroll
    for (int msk = 1; msk < 64; msk <<= 1) M = fmaxf(M, __shfl_xor(M, msk, 64));
    const float cl = __expf(m - M);
    float lw = l * cl, sw = sacc * cl;
    #pragma unroll
    for (int msk = 1; msk < 64; msk <<= 1) {
        lw += __shfl_xor(lw, msk, 64);
        sw += __shfl_xor(sw, msk, 64);
    }
    #pragma unroll
    for (int a = 0; a < A_; ++a) {
        float v = acc[a] * cl;
        #pragma unroll
        for (int msk = 1; msk < 64; msk <<= 1) v += __shfl_xor(v, msk, 64);
        acc[a] = v;                       // identical on all lanes
    }
    // fold scalar Q-side accumulator:  step ∝ Σw·V + (Σw·a2c)·Q
    #pragma unroll
    for (int a = 0; a < A_; ++a) acc[a] = fmaf(sw, qr[a], acc[a]);

    // ---- epilogue (redundant across lanes; lane 0 stores) ----
    const float un_const = sqrtf(TINYF);
    const float inv_l = 1.0f / lw;
    #pragma unroll
    for (int a = 0; a < A_; ++a) acc[a] = (acc[a] * inv_l) / un_const;

    float mk = -acc[0] * acc[0];
    #pragma unroll
    for (int a = 1; a < A_; ++a) mk = fmaf(acc[a], acc[a], mk);
    const float snorm = sqrtf(fmaxf(mk, TINYF));
    const float fac   = fminf(snorm, 20.0f) / (snorm + 1e-9f);
    #pragma unroll
    for (int a = 0; a < A_; ++a) acc[a] *= fac;

    float mk2 = -acc[0] * acc[0];
    #pragma unroll
    for (int a = 1; a < A_; ++a) mk2 = fmaf(acc[a], acc[a], mk2);
    const float vn  = sqrtf(fmaxf(mk2, TINYF));
    const float ch  = coshf(vn);
    const float shr = sinhf(vn) / fmaxf(vn, TINYF);
    #pragma unroll
    for (int a = 0; a < A_; ++a) acc[a] = fmaf(ch, qr[a], shr * acc[a]);  // y

    float xx = -acc[0] * acc[0];
    #pragma unroll
    for (int a = 1; a < A_; ++a) xx = fmaf(acc[a], acc[a], xx);
    const float scale = sqrtf(fmaxf(fabsf(xx), TINYF));

    const float Y0  = fabsf(acc[0] / scale);
    const float al3 = fminf(fmaxf(Y0, 1.0f + EPSF), MAX_ACOSH_ARGF);
    const float d3  = acoshf(al3);
    const float u0  = Y0 + al3;
    const float f3  = d3 / fmaxf(un_const, TINYF);

    if (lane == 0) {
        const int b = bh >> 3, h = bh & 7, qi = q0 + wid;
        float* zp = ZT + (b * T_ + qi) * HA + h * A_;
        zp[0] = f3 * u0;
        const float fsc = f3 / scale;
        #pragma unroll
        for (int a = 1; a < A_; ++a) zp[a] = fsc * acc[a];
    }
}

// ---------------- Kernel 3: Z = Z_tan @ Wo + bo (64x64 tile, BK=44) -----------
__global__ __launch_bounds__(256) void out_kernel(
    const float* __restrict__ ZT, const float* __restrict__ Wo,
    const float* __restrict__ bo, float* __restrict__ out)
{
    __shared__ float smem[2816 + 2860];
    float* zs = smem;            // [64][44]
    float* wt = smem + 2816;     // [44][65]
    const int m0 = blockIdx.x * 64, n0 = blockIdx.y * 64;
    const int tid = threadIdx.x;
    const int tx = tid & 15, ty = tid >> 4;

    float acc[4][4];
    #pragma unroll
    for (int j = 0; j < 4; ++j) {
        const float bv_ = bo[n0 + tx + 16 * j];
        #pragma unroll
        for (int i = 0; i < 4; ++i) acc[i][j] = bv_;
    }

    for (int kb = 0; kb < HA; kb += 44) {
        __syncthreads();
        for (int idx = tid; idx < 704; idx += 256) {        // zs: 64 x 11 float4
            const int r = idx / 11, c4 = idx % 11;
            const float4 v = *(const float4*)(ZT + (m0 + r) * HA + kb + c4 * 4);
            *(float4*)(zs + r * 44 + c4 * 4) = v;
        }
        for (int idx = tid; idx < 704; idx += 256) {        // wt: 44 x 16 float4
            const int kk = idx >> 4, c4 = idx & 15;
            const float4 v = *(const float4*)(Wo + (kb + kk) * 512 + n0 + c4 * 4);
            float* dst = wt + kk * 65 + c4 * 4;
            dst[0] = v.x; dst[1] = v.y; dst[2] = v.z; dst[3] = v.w;
        }
        __syncthreads();
        #pragma unroll 4
        for (int kk = 0; kk < 44; ++kk) {
            float a[4], bb[4];
            #pragma unroll
            for (int i = 0; i < 4; ++i) a[i] = zs[(ty + 16 * i) * 44 + kk];
            #pragma unroll
            for (int j = 0; j < 4; ++j) bb[j] = wt[kk * 65 + tx + 16 * j];
            #pragma unroll
            for (int i = 0; i < 4; ++i)
                #pragma unroll
                for (int j = 0; j < 4; ++j)
                    acc[i][j] = fmaf(a[i], bb[j], acc[i][j]);
        }
    }
    #pragma unroll
    for (int i = 0; i < 4; ++i)
        #pragma unroll
        for (int j = 0; j < 4; ++j)
            out[(m0 + ty + 16 * i) * 512 + n0 + tx + 16 * j] = acc[i][j];
}

extern "C" void kernel_launch(void* const* d_in, const int* in_sizes, int n_in,
                              void* d_out, int out_size, void* d_ws, size_t ws_size,
                              hipStream_t stream) {
    const float* x  = (const float*)d_in[0];
    const float* Wq = (const float*)d_in[1];
    const float* bq = (const float*)d_in[2];
    const float* Wk = (const float*)d_in[3];
    const float* bk = (const float*)d_in[4];
    const float* Wv = (const float*)d_in[5];
    const float* bv = (const float*)d_in[6];
    const float* Wo = (const float*)d_in[7];
    const float* bo = (const float*)d_in[8];
    float* out = (float*)d_out;
    float* ws  = (float*)d_ws;

    float* Q  = ws;
    float* K  = ws + QSZ;
    float* V  = ws + 2 * QSZ;
    float* ZT = ws + 3 * QSZ;

    qkv_lift_kernel<<<dim3(16, 12), 256, 0, stream>>>(x, Wq, bq, Wk, bk, Wv, bv, Q, K, V);
    attn_kernel<<<1024, 512, 0, stream>>>(Q, K, V, ZT);
    out_kernel<<<dim3(16, 8), 256, 0, stream>>>(ZT, Wo, bo, out);
}

// Round 4
// 176.389 us; speedup vs baseline: 1.7256x; 1.2281x over previous
//
#include <hip/hip_runtime.h>
#include <hip/hip_bf16.h>
#include <math.h>

#define EPSF 1e-6f
#define MAX_ACOSH_ARGF 1e6f
#define MAX_DISTF 50.0f
#define TINYF 1e-15f

constexpr int B_ = 2, T_ = 512, D_ = 512, H_ = 8, N_ = 32, A_ = 33;
constexpr int QSZ = B_ * H_ * T_ * A_;   // 270336 floats per tensor
constexpr int HA = H_ * A_;              // 264

__device__ __forceinline__ float facosh(float a) {
    // a >= 1+EPS guaranteed by clamp; (a-1)(a+1) avoids a*a-1 cancellation
    return __logf(a + sqrtf((a - 1.0f) * (a + 1.0f)));
}

// ---------------- Kernel 1: QKV GEMM (32x64 tile, dbuf prefetch) + lift -------
__global__ __launch_bounds__(256) void qkv_lift_kernel(
    const float* __restrict__ x,
    const float* __restrict__ Wq, const float* __restrict__ bq,
    const float* __restrict__ Wk, const float* __restrict__ bk,
    const float* __restrict__ Wv, const float* __restrict__ bv,
    float* __restrict__ Q, float* __restrict__ K, float* __restrict__ V)
{
    __shared__ __align__(16) float smem[3232];   // xs[32][36] | wt[32][65]; Ct[32][65] reuse
    float* xs = smem;                            // 1152
    float* wt = smem + 1152;                     // 2080
    float* Ct = smem;

    const int m0   = blockIdx.x * 32;            // bt tile (32 rows)
    const int ny   = blockIdx.y;                 // 0..11
    const int tsel = ny >> 2;
    const int n0t  = (ny & 3) * 64;
    const float* W    = (tsel == 0) ? Wq : (tsel == 1) ? Wk : Wv;
    const float* bias = (tsel == 0) ? bq : (tsel == 1) ? bk : bv;
    float* OUT        = (tsel == 0) ? Q  : (tsel == 1) ? K  : V;

    const int tid = threadIdx.x;
    const int tx = tid & 15, ty = tid >> 4;

    float acc[2][4];
    #pragma unroll
    for (int j = 0; j < 4; ++j) {
        const float bv_ = bias[n0t + tx + 16 * j];
        acc[0][j] = bv_; acc[1][j] = bv_;
    }

    // prefetch registers
    const int xr = tid >> 3, xc = (tid & 7) * 4;     // x tile: 32 x 32
    const int wr = tid >> 4, wc = (tid & 15) * 4;    // w tile: 32 x 64 (2 halves)
    float4 px, pw0, pw1;
    px  = *(const float4*)(x + (m0 + xr) * 512 + 0 + xc);
    pw0 = *(const float4*)(W + (0 + wr) * 256 + n0t + wc);
    pw1 = *(const float4*)(W + (16 + wr) * 256 + n0t + wc);

    for (int kb = 0; kb < 512; kb += 32) {
        *(float4*)(xs + xr * 36 + xc) = px;
        {
            float* d0 = wt + wr * 65 + wc;
            d0[0] = pw0.x; d0[1] = pw0.y; d0[2] = pw0.z; d0[3] = pw0.w;
            float* d1 = wt + (wr + 16) * 65 + wc;
            d1[0] = pw1.x; d1[1] = pw1.y; d1[2] = pw1.z; d1[3] = pw1.w;
        }
        __syncthreads();
        if (kb + 32 < 512) {
            px  = *(const float4*)(x + (m0 + xr) * 512 + (kb + 32) + xc);
            pw0 = *(const float4*)(W + (kb + 32 + wr) * 256 + n0t + wc);
            pw1 = *(const float4*)(W + (kb + 48 + wr) * 256 + n0t + wc);
        }
        #pragma unroll 8
        for (int kk = 0; kk < 32; ++kk) {
            const float a0 = xs[ty * 36 + kk];
            const float a1 = xs[(ty + 16) * 36 + kk];
            float bb[4];
            #pragma unroll
            for (int j = 0; j < 4; ++j) bb[j] = wt[kk * 65 + tx + 16 * j];
            #pragma unroll
            for (int j = 0; j < 4; ++j) {
                acc[0][j] = fmaf(a0, bb[j], acc[0][j]);
                acc[1][j] = fmaf(a1, bb[j], acc[1][j]);
            }
        }
        __syncthreads();
    }

    #pragma unroll
    for (int i = 0; i < 2; ++i)
        #pragma unroll
        for (int j = 0; j < 4; ++j)
            Ct[(ty + 16 * i) * 65 + tx + 16 * j] = acc[i][j];
    __syncthreads();

    if (tid < 64) {
        const int row = tid >> 1, g = tid & 1;       // 32 rows x 2 head-groups
        const float* u = Ct + row * 65 + g * 32;
        float n2 = 0.0f;
        #pragma unroll
        for (int kk = 0; kk < 32; ++kk) n2 = fmaf(u[kk], u[kk], n2);
        n2 = fmaxf(n2, TINYF);
        const float vn = sqrtf(n2);
        const float ch = coshf(vn);
        const float sh = sinhf(vn) / fmaxf(vn, TINYF);
        const float xx = fmaf(sh * sh, n2, -ch * ch);
        const float scale = sqrtf(fmaxf(fabsf(xx), TINYF));
        const int bt = m0 + row;
        const int b = bt >> 9, t = bt & 511;
        const int h = (n0t >> 5) + g;
        const int base = ((b * H_ + h) * T_ + t) * A_;
        OUT[base] = fabsf(ch / scale);
        const float fs = sh / scale;
        #pragma unroll
        for (int kk = 0; kk < 32; ++kk) OUT[base + 1 + kk] = fs * u[kk];
    }
}

// ---------------- Kernel 2: attention + Karcher step + log-map ----------------
// 256 blocks = 16 bh x 16 q-tiles of 32 q. 512 threads = 8 waves x 4 groups(16).
// Each 16-lane group owns one q; lane t handles k = t + 16*step (32 steps).
// K/V double-buffered in 64-row LDS chunks; one barrier per chunk.
__global__ __launch_bounds__(512) void attn_kernel(
    const float* __restrict__ Q, const float* __restrict__ K,
    const float* __restrict__ V, float* __restrict__ ZT)
{
    __shared__ __align__(16) float sm[2 * 4608 + 1056];  // 2 x (K[64][36]+V[64][36]) + Qs[32][33]
    float* Qs = sm + 9216;

    const int blk = blockIdx.x;           // 256
    const int bh  = blk >> 4;
    const int q0  = (blk & 15) * 32;
    const int tid = threadIdx.x;
    const int t   = tid & 15;             // lane within group
    const int ql  = tid >> 4;             // 0..31: q index within block

    const float* Kg = K + bh * (T_ * A_);
    const float* Vg = V + bh * (T_ * A_);
    const float* Qg = Q + (bh * T_ + q0) * A_;

    // ---- stage chunk 0 + Q ----
    {
        float* bK = sm;
        float* bV = sm + 2304;
        for (int idx = tid; idx < 2112; idx += 512) {
            const int r = idx / 33, c = idx - r * 33;
            bK[r * 36 + c] = Kg[idx];
            bV[r * 36 + c] = Vg[idx];
        }
        for (int idx = tid; idx < 1056; idx += 512) Qs[idx] = Qg[idx];
    }
    __syncthreads();

    // q row with spatial components negated: alpha = dot(qn, k)
    float qn[A_];
    qn[0] = Qs[ql * 33];
    #pragma unroll
    for (int a = 1; a < A_; ++a) qn[a] = -Qs[ql * 33 + a];

    float m = -3.0e38f, l = 0.0f, sacc = 0.0f;
    float acc[A_];
    #pragma unroll
    for (int a = 0; a < A_; ++a) acc[a] = 0.0f;

    for (int c = 0; c < 8; ++c) {
        if (c < 7) {  // stage next chunk into other buffer (overlaps compute)
            float* bK = sm + ((c + 1) & 1) * 4608;
            float* bV = bK + 2304;
            const float* Kc = Kg + (c + 1) * 2112;
            const float* Vc = Vg + (c + 1) * 2112;
            for (int idx = tid; idx < 2112; idx += 512) {
                const int r = idx / 33, cc = idx - r * 33;
                bK[r * 36 + cc] = Kc[idx];
                bV[r * 36 + cc] = Vc[idx];
            }
        }
        const float* bK = sm + (c & 1) * 4608;
        const float* bV = bK + 2304;

        #pragma unroll 2
        for (int sp = 0; sp < 4; ++sp) {
            const float* kr = bK + (t + 16 * sp) * 36;
            const float* vr = bV + (t + 16 * sp) * 36;
            float kk[A_];
            #pragma unroll
            for (int j = 0; j < 8; ++j) *(float4*)&kk[4 * j] = *(const float4*)(kr + 4 * j);
            kk[32] = kr[32];
            float p0 = qn[32] * kk[32], p1 = 0.f, p2 = 0.f, p3 = 0.f;
            #pragma unroll
            for (int j = 0; j < 8; ++j) {
                p0 = fmaf(qn[4 * j],     kk[4 * j],     p0);
                p1 = fmaf(qn[4 * j + 1], kk[4 * j + 1], p1);
                p2 = fmaf(qn[4 * j + 2], kk[4 * j + 2], p2);
                p3 = fmaf(qn[4 * j + 3], kk[4 * j + 3], p3);
            }
            const float a1 = (p0 + p1) + (p2 + p3);

            float vv[A_];
            #pragma unroll
            for (int j = 0; j < 8; ++j) *(float4*)&vv[4 * j] = *(const float4*)(vr + 4 * j);
            vv[32] = vr[32];
            float r0 = qn[32] * vv[32], r1 = 0.f, r2 = 0.f, r3 = 0.f;
            #pragma unroll
            for (int j = 0; j < 8; ++j) {
                r0 = fmaf(qn[4 * j],     vv[4 * j],     r0);
                r1 = fmaf(qn[4 * j + 1], vv[4 * j + 1], r1);
                r2 = fmaf(qn[4 * j + 2], vv[4 * j + 2], r2);
                r3 = fmaf(qn[4 * j + 3], vv[4 * j + 3], r3);
            }
            const float a2 = (r0 + r1) + (r2 + r3);

            const float a1c = fminf(fmaxf(a1, 1.0f + EPSF), MAX_ACOSH_ARGF);
            const float d1  = fminf(facosh(a1c), MAX_DISTF);
            const float sN  = -d1 * d1;
            const float a2c = fminf(fmaxf(a2, 1.0f + EPSF), MAX_ACOSH_ARGF);
            const float d2  = facosh(a2c);

            if (sN > m) {          // deferred rescale (rare after warm-up)
                const float cr = __expf(m - sN);
                l *= cr; sacc *= cr;
                #pragma unroll
                for (int a = 0; a < A_; ++a) acc[a] *= cr;
                m = sN;
            }
            const float e = __expf(sN - m);
            l += e;
            const float w = e * d2;
            sacc = fmaf(w, a2c, sacc);
            #pragma unroll
            for (int a = 0; a < A_; ++a) acc[a] = fmaf(w, vv[a], acc[a]);
        }
        __syncthreads();
    }

    // ---- 16-lane group merge: max, scale once, butterfly sums ----
    float M = m;
    #pragma unroll
    for (int msk = 1; msk < 16; msk <<= 1) M = fmaxf(M, __shfl_xor(M, msk, 64));
    const float cl = __expf(m - M);
    float lw = l * cl, sw = sacc * cl;
    #pragma unroll
    for (int msk = 1; msk < 16; msk <<= 1) {
        lw += __shfl_xor(lw, msk, 64);
        sw += __shfl_xor(sw, msk, 64);
    }
    #pragma unroll
    for (int a = 0; a < A_; ++a) {
        float v = acc[a] * cl;
        #pragma unroll
        for (int msk = 1; msk < 16; msk <<= 1) v += __shfl_xor(v, msk, 64);
        acc[a] = v;
    }
    // fold scalar Q-side accumulator: step ∝ Σw·V + (Σw·a2c)·Q ; qr = (qn0, -qn[i])
    const float nsw = -sw;
    acc[0] = fmaf(sw, qn[0], acc[0]);
    #pragma unroll
    for (int a = 1; a < A_; ++a) acc[a] = fmaf(nsw, qn[a], acc[a]);

    // ---- epilogue (redundant within group; lane t==0 stores) ----
    const float un_const = sqrtf(TINYF);
    const float inv_l = 1.0f / lw;
    #pragma unroll
    for (int a = 0; a < A_; ++a) acc[a] = (acc[a] * inv_l) / un_const;

    float mk = -acc[0] * acc[0];
    #pragma unroll
    for (int a = 1; a < A_; ++a) mk = fmaf(acc[a], acc[a], mk);
    const float snorm = sqrtf(fmaxf(mk, TINYF));
    const float fac   = fminf(snorm, 20.0f) / (snorm + 1e-9f);
    #pragma unroll
    for (int a = 0; a < A_; ++a) acc[a] *= fac;

    float mk2 = -acc[0] * acc[0];
    #pragma unroll
    for (int a = 1; a < A_; ++a) mk2 = fmaf(acc[a], acc[a], mk2);
    const float vn  = sqrtf(fmaxf(mk2, TINYF));
    const float ch  = coshf(vn);
    const float shr = sinhf(vn) / fmaxf(vn, TINYF);
    const float nch = -ch;
    acc[0] = fmaf(ch, qn[0], shr * acc[0]);
    #pragma unroll
    for (int a = 1; a < A_; ++a) acc[a] = fmaf(nch, qn[a], shr * acc[a]);  // y

    float xx = -acc[0] * acc[0];
    #pragma unroll
    for (int a = 1; a < A_; ++a) xx = fmaf(acc[a], acc[a], xx);
    const float scale = sqrtf(fmaxf(fabsf(xx), TINYF));

    const float Y0  = fabsf(acc[0] / scale);
    const float al3 = fminf(fmaxf(Y0, 1.0f + EPSF), MAX_ACOSH_ARGF);
    const float d3  = acoshf(al3);
    const float u0  = Y0 + al3;
    const float f3  = d3 / fmaxf(un_const, TINYF);

    if (t == 0) {
        const int b = bh >> 3, h = bh & 7, qi = q0 + ql;
        float* zp = ZT + (b * T_ + qi) * HA + h * A_;
        zp[0] = f3 * u0;
        const float fsc = f3 / scale;
        #pragma unroll
        for (int a = 1; a < A_; ++a) zp[a] = fsc * acc[a];
    }
}

// ---------------- Kernel 3: Z = Z_tan @ Wo + bo (32x64 tile, BK=44, prefetch) -
__global__ __launch_bounds__(256) void out_kernel(
    const float* __restrict__ ZT, const float* __restrict__ Wo,
    const float* __restrict__ bo, float* __restrict__ out)
{
    __shared__ __align__(16) float smem[1408 + 2860];
    float* zs = smem;            // [32][44]
    float* wt = smem + 1408;     // [44][65]
    const int m0 = blockIdx.x * 32, n0 = blockIdx.y * 64;
    const int tid = threadIdx.x;
    const int tx = tid & 15, ty = tid >> 4;

    float acc[2][4];
    #pragma unroll
    for (int j = 0; j < 4; ++j) {
        const float bv_ = bo[n0 + tx + 16 * j];
        acc[0][j] = bv_; acc[1][j] = bv_;
    }

    // prefetch registers: zs 352 f4 (2 rounds), wt 704 f4 (3 rounds)
    const int zr0 = tid / 11,        zc0 = (tid - zr0 * 11) * 4;
    const int zi1 = tid + 256;
    const int zr1 = zi1 / 11,        zc1 = (zi1 - zr1 * 11) * 4;
    const bool zv1 = tid < 96;
    const int wr0 = tid >> 4,        wc0 = (tid & 15) * 4;     // rows 0..15
    const int wr1 = wr0 + 16, wr2 = wr0 + 32;                  // rows 16..31, 32..47
    const bool wv2 = tid < 192;                                // rows 32..43

    float4 pz0, pz1, pw0, pw1, pw2;
    pz0 = *(const float4*)(ZT + (m0 + zr0) * HA + 0 + zc0);
    if (zv1) pz1 = *(const float4*)(ZT + (m0 + zr1) * HA + 0 + zc1);
    pw0 = *(const float4*)(Wo + (0 + wr0) * 512 + n0 + wc0);
    pw1 = *(const float4*)(Wo + (0 + wr1) * 512 + n0 + wc0);
    if (wv2) pw2 = *(const float4*)(Wo + (0 + wr2) * 512 + n0 + wc0);

    for (int kb = 0; kb < HA; kb += 44) {
        *(float4*)(zs + zr0 * 44 + zc0) = pz0;
        if (zv1) *(float4*)(zs + zr1 * 44 + zc1) = pz1;
        {
            float* d = wt + wr0 * 65 + wc0;
            d[0] = pw0.x; d[1] = pw0.y; d[2] = pw0.z; d[3] = pw0.w;
            d = wt + wr1 * 65 + wc0;
            d[0] = pw1.x; d[1] = pw1.y; d[2] = pw1.z; d[3] = pw1.w;
            if (wv2) {
                d = wt + wr2 * 65 + wc0;
                d[0] = pw2.x; d[1] = pw2.y; d[2] = pw2.z; d[3] = pw2.w;
            }
        }
        __syncthreads();
        if (kb + 44 < HA) {
            pz0 = *(const float4*)(ZT + (m0 + zr0) * HA + (kb + 44) + zc0);
            if (zv1) pz1 = *(const float4*)(ZT + (m0 + zr1) * HA + (kb + 44) + zc1);
            pw0 = *(const float4*)(Wo + (kb + 44 + wr0) * 512 + n0 + wc0);
            pw1 = *(const float4*)(Wo + (kb + 44 + wr1) * 512 + n0 + wc0);
            if (wv2) pw2 = *(const float4*)(Wo + (kb + 44 + wr2) * 512 + n0 + wc0);
        }
        #pragma unroll 4
        for (int kk = 0; kk < 44; ++kk) {
            const float a0 = zs[ty * 44 + kk];
            const float a1 = zs[(ty + 16) * 44 + kk];
            float bb[4];
            #pragma unroll
            for (int j = 0; j < 4; ++j) bb[j] = wt[kk * 65 + tx + 16 * j];
            #pragma unroll
            for (int j = 0; j < 4; ++j) {
                acc[0][j] = fmaf(a0, bb[j], acc[0][j]);
                acc[1][j] = fmaf(a1, bb[j], acc[1][j]);
            }
        }
        __syncthreads();
    }
    #pragma unroll
    for (int i = 0; i < 2; ++i)
        #pragma unroll
        for (int j = 0; j < 4; ++j)
            out[(m0 + ty + 16 * i) * 512 + n0 + tx + 16 * j] = acc[i][j];
}

extern "C" void kernel_launch(void* const* d_in, const int* in_sizes, int n_in,
                              void* d_out, int out_size, void* d_ws, size_t ws_size,
                              hipStream_t stream) {
    const float* x  = (const float*)d_in[0];
    const float* Wq = (const float*)d_in[1];
    const float* bq = (const float*)d_in[2];
    const float* Wk = (const float*)d_in[3];
    const float* bk = (const float*)d_in[4];
    const float* Wv = (const float*)d_in[5];
    const float* bv = (const float*)d_in[6];
    const float* Wo = (const float*)d_in[7];
    const float* bo = (const float*)d_in[8];
    float* out = (float*)d_out;
    float* ws  = (float*)d_ws;

    float* Q  = ws;
    float* K  = ws + QSZ;
    float* V  = ws + 2 * QSZ;
    float* ZT = ws + 3 * QSZ;

    qkv_lift_kernel<<<dim3(32, 12), 256, 0, stream>>>(x, Wq, bq, Wk, bk, Wv, bv, Q, K, V);
    attn_kernel<<<256, 512, 0, stream>>>(Q, K, V, ZT);
    out_kernel<<<dim3(32, 8), 256, 0, stream>>>(ZT, Wo, bo, out);
}